// Round 1
// baseline (16603.999 us; speedup 1.0000x reference)
//
#include <hip/hip_runtime.h>

// GraphSAGE 3-layer: N=100000 nodes, E=3.2M edges, 128 -> 128 -> 128 -> 64.
// out_l = relu?( (agg/cnt) @ Wl^T + bl + h @ Wr^T )
// Structure per call:
//   - transpose all W into ws (coalesced B for GEMM)
//   - degree count (once; same edges for all layers)
//   - per layer: zero agg, scatter-add h[src] -> agg[dst], fused GEMM
// ws layout: hbuf (N*128 f32) | agg (N*128 f32) | cnt (N f32) | 6 transposed W

#define NN 100000

__global__ void count_kernel(const int* __restrict__ dst, float* __restrict__ cnt, int E) {
    int t = blockIdx.x * blockDim.x + threadIdx.x;
    if (t < E) unsafeAtomicAdd(&cnt[dst[t]], 1.0f);
}

// 32 threads per edge, float4 each: C=128 floats per row.
__global__ void scatter_kernel(const float* __restrict__ h, const int* __restrict__ src,
                               const int* __restrict__ dst, float* __restrict__ agg, int E) {
    long long t = (long long)blockIdx.x * blockDim.x + threadIdx.x;
    int edge = (int)(t >> 5);
    if (edge >= E) return;
    int lane = (int)(t & 31);
    int s = src[edge], d = dst[edge];
    const float4 v = *(const float4*)(h + (size_t)s * 128 + lane * 4);
    float* a = agg + (size_t)d * 128 + lane * 4;
    unsafeAtomicAdd(a + 0, v.x);
    unsafeAtomicAdd(a + 1, v.y);
    unsafeAtomicAdd(a + 2, v.z);
    unsafeAtomicAdd(a + 3, v.w);
}

// W (rows x cols) -> WT (cols x rows)
__global__ void transpose_kernel(const float* __restrict__ W, float* __restrict__ WT,
                                 int rows, int cols) {
    int t = blockIdx.x * blockDim.x + threadIdx.x;
    if (t < rows * cols) {
        int r = t / cols, c = t % cols;
        WT[(size_t)c * rows + r] = W[(size_t)r * cols + c];
    }
}

// Fused: out[n][j] = relu?( sum_k (agg[n][k]*inv[n]) * WlT[k][j] + sum_k h[n][k]*WrT[k][j] + bias[j] )
// Tile: 64 nodes x C_OUT per 256-thread block. K chunks of 16.
template <int C_IN, int C_OUT, bool RELU>
__global__ __launch_bounds__(256) void fused_layer(
    const float* __restrict__ h, const float* __restrict__ agg, const float* __restrict__ cnt,
    const float* __restrict__ WlT, const float* __restrict__ WrT, const float* __restrict__ bias,
    float* __restrict__ out, int n) {
    constexpr int JW = C_OUT / 16;  // 8 for 128, 4 for 64
    __shared__ float a_s[64][20];
    __shared__ float b_s[16][C_OUT + 4];
    __shared__ float inv_s[64];
    int tid = threadIdx.x;
    int m0 = blockIdx.x * 64;
    if (tid < 64) {
        int node = m0 + tid;
        inv_s[tid] = (node < n) ? 1.0f / fmaxf(cnt[node], 1.0f) : 0.0f;
    }
    __syncthreads();
    int tm = tid >> 4, tj = tid & 15;
    float acc[4][JW];
#pragma unroll
    for (int i = 0; i < 4; i++)
#pragma unroll
        for (int jj = 0; jj < JW; jj++) acc[i][jj] = 0.0f;

    for (int stage = 0; stage < 2; stage++) {
        const float* A = stage == 0 ? agg : h;
        const float* B = stage == 0 ? WlT : WrT;
        for (int kc = 0; kc < C_IN / 16; kc++) {
            int k0 = kc * 16;
            {  // A tile: 64 rows x 16 cols, one float4 per thread
                int r = tid >> 2;
                int c = (tid & 3) * 4;
                int node = m0 + r;
                float4 v = make_float4(0.f, 0.f, 0.f, 0.f);
                if (node < n) v = *(const float4*)(A + (size_t)node * C_IN + k0 + c);
                float s = (stage == 0) ? inv_s[r] : 1.0f;
                a_s[r][c + 0] = v.x * s;
                a_s[r][c + 1] = v.y * s;
                a_s[r][c + 2] = v.z * s;
                a_s[r][c + 3] = v.w * s;
            }
            {  // B tile: 16 x C_OUT
                constexpr int T4 = 16 * C_OUT / 4;
#pragma unroll
                for (int idx = 0; idx < T4; idx += 256) {
                    int ii = idx + tid;
                    int r = ii / (C_OUT / 4);
                    int c = (ii % (C_OUT / 4)) * 4;
                    float4 v = *(const float4*)(B + (size_t)(k0 + r) * C_OUT + c);
                    *(float4*)&b_s[r][c] = v;
                }
            }
            __syncthreads();
#pragma unroll
            for (int k = 0; k < 16; k++) {
                float av[4];
#pragma unroll
                for (int i = 0; i < 4; i++) av[i] = a_s[tm * 4 + i][k];
                float bv[JW];
#pragma unroll
                for (int jj = 0; jj < JW; jj++) bv[jj] = b_s[k][tj * JW + jj];
#pragma unroll
                for (int i = 0; i < 4; i++)
#pragma unroll
                    for (int jj = 0; jj < JW; jj++) acc[i][jj] += av[i] * bv[jj];
            }
            __syncthreads();
        }
    }
#pragma unroll
    for (int i = 0; i < 4; i++) {
        int node = m0 + tm * 4 + i;
        if (node < n) {
#pragma unroll
            for (int jj = 0; jj < JW; jj++) {
                int j = tj * JW + jj;
                float v = acc[i][jj] + bias[j];
                if (RELU) v = fmaxf(v, 0.0f);
                out[(size_t)node * C_OUT + j] = v;
            }
        }
    }
}

extern "C" void kernel_launch(void* const* d_in, const int* in_sizes, int n_in,
                              void* d_out, int out_size, void* d_ws, size_t ws_size,
                              hipStream_t stream) {
    const float* x   = (const float*)d_in[0];
    const int*   ei  = (const int*)d_in[1];
    const float* Wl1 = (const float*)d_in[2];
    const float* bl1 = (const float*)d_in[3];
    const float* Wr1 = (const float*)d_in[4];
    const float* Wl2 = (const float*)d_in[5];
    const float* bl2 = (const float*)d_in[6];
    const float* Wr2 = (const float*)d_in[7];
    const float* Wl3 = (const float*)d_in[8];
    const float* bl3 = (const float*)d_in[9];
    const float* Wr3 = (const float*)d_in[10];

    const int N = NN;
    const int E = in_sizes[1] / 2;
    const int* src = ei;
    const int* dst = ei + E;

    char* ws = (char*)d_ws;
    float* hbuf = (float*)ws;                                   // N*128 f32
    float* agg  = (float*)(ws + (size_t)N * 128 * 4);           // N*128 f32
    float* cnt  = (float*)(ws + (size_t)N * 128 * 4 * 2);       // N f32
    float* wt   = (float*)(ws + (size_t)N * 128 * 4 * 2 + (size_t)N * 4);
    float* WlT1 = wt;
    float* WrT1 = WlT1 + 128 * 128;
    float* WlT2 = WrT1 + 128 * 128;
    float* WrT2 = WlT2 + 128 * 128;
    float* WlT3 = WrT2 + 128 * 128;  // 128x64
    float* WrT3 = WlT3 + 128 * 64;

    // Transpose weights (tiny)
    transpose_kernel<<<64, 256, 0, stream>>>(Wl1, WlT1, 128, 128);
    transpose_kernel<<<64, 256, 0, stream>>>(Wr1, WrT1, 128, 128);
    transpose_kernel<<<64, 256, 0, stream>>>(Wl2, WlT2, 128, 128);
    transpose_kernel<<<64, 256, 0, stream>>>(Wr2, WrT2, 128, 128);
    transpose_kernel<<<32, 256, 0, stream>>>(Wl3, WlT3, 64, 128);
    transpose_kernel<<<32, 256, 0, stream>>>(Wr3, WrT3, 64, 128);

    // Degree count (same for all layers)
    hipMemsetAsync(cnt, 0, (size_t)N * 4, stream);
    count_kernel<<<(E + 255) / 256, 256, 0, stream>>>(dst, cnt, E);

    const long long sc_threads = (long long)E * 32;
    const int sc_blocks = (int)((sc_threads + 255) / 256);
    const int gemm_blocks = (N + 63) / 64;

    // Layer 1: x -> hbuf (relu)
    hipMemsetAsync(agg, 0, (size_t)N * 128 * 4, stream);
    scatter_kernel<<<sc_blocks, 256, 0, stream>>>(x, src, dst, agg, E);
    fused_layer<128, 128, true><<<gemm_blocks, 256, 0, stream>>>(
        x, agg, cnt, WlT1, WrT1, bl1, hbuf, N);

    // Layer 2: hbuf -> hbuf in place (row-local, safe) (relu)
    hipMemsetAsync(agg, 0, (size_t)N * 128 * 4, stream);
    scatter_kernel<<<sc_blocks, 256, 0, stream>>>(hbuf, src, dst, agg, E);
    fused_layer<128, 128, true><<<gemm_blocks, 256, 0, stream>>>(
        hbuf, agg, cnt, WlT2, WrT2, bl2, hbuf, N);

    // Layer 3: hbuf -> d_out (no relu), C_OUT=64
    hipMemsetAsync(agg, 0, (size_t)N * 128 * 4, stream);
    scatter_kernel<<<sc_blocks, 256, 0, stream>>>(hbuf, src, dst, agg, E);
    fused_layer<128, 64, false><<<gemm_blocks, 256, 0, stream>>>(
        hbuf, agg, cnt, WlT3, WrT3, bl3, (float*)d_out, N);
}

// Round 2
// 1649.396 us; speedup vs baseline: 10.0667x; 10.0667x over previous
//
#include <hip/hip_runtime.h>

// GraphSAGE 3-layer: N=100000 nodes, E=3.2M edges, 128 -> 128 -> 128 -> 64.
// Round 2: replace atomic scatter (atomic-pipeline bound, 3x5.35ms) with
// counting-sort CSR build (once per call) + gather-based segmented mean
// (zero float atomics). mean folded into aggregation kernel.
// ws layout: hbuf | mean | cnt(int) | row_ptr | fill | sorted_src | 6 W^T

#define NN 100000

__global__ void count_kernel(const int* __restrict__ dst, int* __restrict__ cnt, int E) {
    int t = blockIdx.x * blockDim.x + threadIdx.x;
    if (t < E) atomicAdd(&cnt[dst[t]], 1);
}

// Single-block exclusive scan over n=100k (1024 threads, ~98 elems each).
__global__ __launch_bounds__(1024) void scan_kernel(const int* __restrict__ cnt,
                                                    int* __restrict__ row_ptr,
                                                    int* __restrict__ fill, int n) {
    __shared__ int sums[1024];
    int tid = threadIdx.x;
    int chunk = (n + 1023) / 1024;
    int lo = tid * chunk;
    int hi = min(lo + chunk, n);
    int s = 0;
    for (int i = lo; i < hi; i++) s += cnt[i];
    sums[tid] = s;
    __syncthreads();
    for (int off = 1; off < 1024; off <<= 1) {
        int v = (tid >= off) ? sums[tid - off] : 0;
        __syncthreads();
        sums[tid] += v;
        __syncthreads();
    }
    int run = (tid == 0) ? 0 : sums[tid - 1];  // exclusive prefix of this chunk
    for (int i = lo; i < hi; i++) {
        row_ptr[i] = run;
        fill[i] = run;
        run += cnt[i];
    }
    if (tid == 1023) row_ptr[n] = run;  // == E (last chunk covers tail)
}

__global__ void bucket_kernel(const int* __restrict__ src, const int* __restrict__ dst,
                              int* __restrict__ fill, int* __restrict__ sorted_src, int E) {
    int t = blockIdx.x * blockDim.x + threadIdx.x;
    if (t < E) {
        int pos = atomicAdd(&fill[dst[t]], 1);
        sorted_src[pos] = src[t];
    }
}

// One 32-thread group per node; lane owns float4 column slice of C=128.
// Gathers h[src] rows over the node's CSR segment, 4-deep unroll for MLP,
// folds mean division, writes mean[node].
__global__ __launch_bounds__(256) void gather_mean_kernel(
    const float* __restrict__ h, const int* __restrict__ row_ptr,
    const int* __restrict__ sorted_src, float* __restrict__ mean, int n) {
    int node = blockIdx.x * 8 + (threadIdx.x >> 5);
    if (node >= n) return;
    int lane = threadIdx.x & 31;
    int beg = row_ptr[node], end = row_ptr[node + 1];
    float ax = 0.f, ay = 0.f, az = 0.f, aw = 0.f;
    int j = beg;
    for (; j + 3 < end; j += 4) {
        int s0 = sorted_src[j], s1 = sorted_src[j + 1];
        int s2 = sorted_src[j + 2], s3 = sorted_src[j + 3];
        float4 v0 = *(const float4*)(h + (size_t)s0 * 128 + lane * 4);
        float4 v1 = *(const float4*)(h + (size_t)s1 * 128 + lane * 4);
        float4 v2 = *(const float4*)(h + (size_t)s2 * 128 + lane * 4);
        float4 v3 = *(const float4*)(h + (size_t)s3 * 128 + lane * 4);
        ax += (v0.x + v1.x) + (v2.x + v3.x);
        ay += (v0.y + v1.y) + (v2.y + v3.y);
        az += (v0.z + v1.z) + (v2.z + v3.z);
        aw += (v0.w + v1.w) + (v2.w + v3.w);
    }
    for (; j < end; j++) {
        int s0 = sorted_src[j];
        float4 v0 = *(const float4*)(h + (size_t)s0 * 128 + lane * 4);
        ax += v0.x; ay += v0.y; az += v0.z; aw += v0.w;
    }
    float inv = (end > beg) ? 1.0f / (float)(end - beg) : 0.0f;
    float4 r = make_float4(ax * inv, ay * inv, az * inv, aw * inv);
    *(float4*)(mean + (size_t)node * 128 + lane * 4) = r;
}

// W (rows x cols) -> WT (cols x rows)
__global__ void transpose_kernel(const float* __restrict__ W, float* __restrict__ WT,
                                 int rows, int cols) {
    int t = blockIdx.x * blockDim.x + threadIdx.x;
    if (t < rows * cols) {
        int r = t / cols, c = t % cols;
        WT[(size_t)c * rows + r] = W[(size_t)r * cols + c];
    }
}

// out[n][j] = relu?( sum_k mean[n][k]*WlT[k][j] + sum_k h[n][k]*WrT[k][j] + bias[j] )
// Tile: 64 nodes x C_OUT per 256-thread block. K chunks of 16.
template <int C_IN, int C_OUT, bool RELU>
__global__ __launch_bounds__(256) void fused_layer(
    const float* __restrict__ h, const float* __restrict__ mean,
    const float* __restrict__ WlT, const float* __restrict__ WrT,
    const float* __restrict__ bias, float* __restrict__ out, int n) {
    constexpr int JW = C_OUT / 16;  // 8 for 128, 4 for 64
    __shared__ float a_s[64][20];
    __shared__ float b_s[16][C_OUT + 4];
    int tid = threadIdx.x;
    int m0 = blockIdx.x * 64;
    int tm = tid >> 4, tj = tid & 15;
    float acc[4][JW];
#pragma unroll
    for (int i = 0; i < 4; i++)
#pragma unroll
        for (int jj = 0; jj < JW; jj++) acc[i][jj] = 0.0f;

    for (int stage = 0; stage < 2; stage++) {
        const float* A = stage == 0 ? mean : h;
        const float* B = stage == 0 ? WlT : WrT;
        for (int kc = 0; kc < C_IN / 16; kc++) {
            int k0 = kc * 16;
            {  // A tile: 64 rows x 16 cols, one float4 per thread
                int r = tid >> 2;
                int c = (tid & 3) * 4;
                int node = m0 + r;
                float4 v = make_float4(0.f, 0.f, 0.f, 0.f);
                if (node < n) v = *(const float4*)(A + (size_t)node * C_IN + k0 + c);
                *(float4*)&a_s[r][c] = v;
            }
            {  // B tile: 16 x C_OUT
                constexpr int T4 = 16 * C_OUT / 4;
#pragma unroll
                for (int idx = 0; idx < T4; idx += 256) {
                    int ii = idx + tid;
                    int r = ii / (C_OUT / 4);
                    int c = (ii % (C_OUT / 4)) * 4;
                    float4 v = *(const float4*)(B + (size_t)(k0 + r) * C_OUT + c);
                    *(float4*)&b_s[r][c] = v;
                }
            }
            __syncthreads();
#pragma unroll
            for (int k = 0; k < 16; k++) {
                float av[4];
#pragma unroll
                for (int i = 0; i < 4; i++) av[i] = a_s[tm * 4 + i][k];
                float bv[JW];
#pragma unroll
                for (int jj = 0; jj < JW; jj++) bv[jj] = b_s[k][tj * JW + jj];
#pragma unroll
                for (int i = 0; i < 4; i++)
#pragma unroll
                    for (int jj = 0; jj < JW; jj++) acc[i][jj] += av[i] * bv[jj];
            }
            __syncthreads();
        }
    }
#pragma unroll
    for (int i = 0; i < 4; i++) {
        int node = m0 + tm * 4 + i;
        if (node < n) {
#pragma unroll
            for (int jj = 0; jj < JW; jj++) {
                int j = tj * JW + jj;
                float v = acc[i][jj] + bias[j];
                if (RELU) v = fmaxf(v, 0.0f);
                out[(size_t)node * C_OUT + j] = v;
            }
        }
    }
}

extern "C" void kernel_launch(void* const* d_in, const int* in_sizes, int n_in,
                              void* d_out, int out_size, void* d_ws, size_t ws_size,
                              hipStream_t stream) {
    const float* x   = (const float*)d_in[0];
    const int*   ei  = (const int*)d_in[1];
    const float* Wl1 = (const float*)d_in[2];
    const float* bl1 = (const float*)d_in[3];
    const float* Wr1 = (const float*)d_in[4];
    const float* Wl2 = (const float*)d_in[5];
    const float* bl2 = (const float*)d_in[6];
    const float* Wr2 = (const float*)d_in[7];
    const float* Wl3 = (const float*)d_in[8];
    const float* bl3 = (const float*)d_in[9];
    const float* Wr3 = (const float*)d_in[10];

    const int N = NN;
    const int E = in_sizes[1] / 2;
    const int* src = ei;
    const int* dst = ei + E;

    char* ws = (char*)d_ws;
    float* hbuf = (float*)ws;                              // N*128 f32
    float* mean = hbuf + (size_t)N * 128;                  // N*128 f32
    int* cnt    = (int*)(mean + (size_t)N * 128);          // N int
    int* row_ptr = cnt + N;                                // N+1 int
    int* fill    = row_ptr + N + 1;                        // N int
    int* sorted_src = fill + N;                            // E int
    float* wt   = (float*)(sorted_src + E);
    float* WlT1 = wt;
    float* WrT1 = WlT1 + 128 * 128;
    float* WlT2 = WrT1 + 128 * 128;
    float* WrT2 = WlT2 + 128 * 128;
    float* WlT3 = WrT2 + 128 * 128;  // 128x64
    float* WrT3 = WlT3 + 128 * 64;

    // Weights transpose (tiny)
    transpose_kernel<<<64, 256, 0, stream>>>(Wl1, WlT1, 128, 128);
    transpose_kernel<<<64, 256, 0, stream>>>(Wr1, WrT1, 128, 128);
    transpose_kernel<<<64, 256, 0, stream>>>(Wl2, WlT2, 128, 128);
    transpose_kernel<<<64, 256, 0, stream>>>(Wr2, WrT2, 128, 128);
    transpose_kernel<<<32, 256, 0, stream>>>(Wl3, WlT3, 64, 128);
    transpose_kernel<<<32, 256, 0, stream>>>(Wr3, WrT3, 64, 128);

    // CSR build: histogram -> scan -> bucket scatter (int atomics only)
    hipMemsetAsync(cnt, 0, (size_t)N * 4, stream);
    count_kernel<<<(E + 255) / 256, 256, 0, stream>>>(dst, cnt, E);
    scan_kernel<<<1, 1024, 0, stream>>>(cnt, row_ptr, fill, N);
    bucket_kernel<<<(E + 255) / 256, 256, 0, stream>>>(src, dst, fill, sorted_src, E);

    const int agg_blocks = (N + 7) / 8;
    const int gemm_blocks = (N + 63) / 64;

    // Layer 1: x -> hbuf (relu)
    gather_mean_kernel<<<agg_blocks, 256, 0, stream>>>(x, row_ptr, sorted_src, mean, N);
    fused_layer<128, 128, true><<<gemm_blocks, 256, 0, stream>>>(
        x, mean, WlT1, WrT1, bl1, hbuf, N);

    // Layer 2: hbuf -> hbuf in place (row-local, safe) (relu)
    gather_mean_kernel<<<agg_blocks, 256, 0, stream>>>(hbuf, row_ptr, sorted_src, mean, N);
    fused_layer<128, 128, true><<<gemm_blocks, 256, 0, stream>>>(
        hbuf, mean, WlT2, WrT2, bl2, hbuf, N);

    // Layer 3: hbuf -> d_out (no relu), C_OUT=64
    gather_mean_kernel<<<agg_blocks, 256, 0, stream>>>(hbuf, row_ptr, sorted_src, mean, N);
    fused_layer<128, 64, false><<<gemm_blocks, 256, 0, stream>>>(
        hbuf, mean, WlT3, WrT3, bl3, (float*)d_out, N);
}

// Round 3
// 1196.789 us; speedup vs baseline: 13.8738x; 1.3782x over previous
//
#include <hip/hip_runtime.h>

// GraphSAGE 3-layer: N=100000, E=3.2M, 128 -> 128 -> 128 -> 64.
// Round 3: fp16 feature path (fp32 accumulate) + MFMA GEMM.
//  - CSR build (count/scan/bucket) unchanged from round 2.
//  - gather_mean reads fp16 h rows (256B), writes fp16 mean.
//  - mfma_layer: LDS-free; A-frags from global (own rows), B-frags from
//    fragment-contiguous prepped weights (L1-hot). fp32 acc, bias+relu epilogue.
// ws: xh | hh | meanh (fp16 N*128) | cnt | row_ptr | fill | sorted_src | 6 prepped W

#define NN 100000

typedef _Float16 half_t;
typedef __attribute__((ext_vector_type(4))) _Float16 half4v;
typedef __attribute__((ext_vector_type(8))) _Float16 half8v;
typedef __attribute__((ext_vector_type(4))) float float4v;

__global__ void count_kernel(const int* __restrict__ dst, int* __restrict__ cnt, int E) {
    int t = blockIdx.x * blockDim.x + threadIdx.x;
    if (t < E) atomicAdd(&cnt[dst[t]], 1);
}

// Single-block exclusive scan over n=100k.
__global__ __launch_bounds__(1024) void scan_kernel(const int* __restrict__ cnt,
                                                    int* __restrict__ row_ptr,
                                                    int* __restrict__ fill, int n) {
    __shared__ int sums[1024];
    int tid = threadIdx.x;
    int chunk = (n + 1023) / 1024;
    int lo = tid * chunk;
    int hi = min(lo + chunk, n);
    int s = 0;
    for (int i = lo; i < hi; i++) s += cnt[i];
    sums[tid] = s;
    __syncthreads();
    for (int off = 1; off < 1024; off <<= 1) {
        int v = (tid >= off) ? sums[tid - off] : 0;
        __syncthreads();
        sums[tid] += v;
        __syncthreads();
    }
    int run = (tid == 0) ? 0 : sums[tid - 1];
    for (int i = lo; i < hi; i++) {
        row_ptr[i] = run;
        fill[i] = run;
        run += cnt[i];
    }
    if (tid == 1023) row_ptr[n] = run;
}

__global__ void bucket_kernel(const int* __restrict__ src, const int* __restrict__ dst,
                              int* __restrict__ fill, int* __restrict__ sorted_src, int E) {
    int t = blockIdx.x * blockDim.x + threadIdx.x;
    if (t < E) {
        int pos = atomicAdd(&fill[dst[t]], 1);
        sorted_src[pos] = src[t];
    }
}

// fp32 -> fp16 cast, 4 elems/thread
__global__ void cast_f2h(const float* __restrict__ in, half_t* __restrict__ out, int n4) {
    int t = blockIdx.x * blockDim.x + threadIdx.x;
    if (t < n4) {
        float4 v = *(const float4*)(in + (size_t)t * 4);
        half4v r = {(half_t)v.x, (half_t)v.y, (half_t)v.z, (half_t)v.w};
        *(half4v*)(out + (size_t)t * 4) = r;
    }
}

// Prep W (C_OUT x C_IN, fp32) into fragment-contiguous fp16 layout:
// B[(((chunk*NCT+ct)*16+c)*4+kq)*8+jj] = W[(ct*16+c)*C_IN + chunk*32+kq*8+jj]
template <int C_IN, int C_OUT>
__global__ void prep_w(const float* __restrict__ W, half_t* __restrict__ B) {
    constexpr int NCT = C_OUT / 16;
    int t = blockIdx.x * blockDim.x + threadIdx.x;
    if (t >= C_IN * C_OUT) return;
    int jj = t & 7;
    int kq = (t >> 3) & 3;
    int c = (t >> 5) & 15;
    int ct = (t >> 9) % NCT;
    int chunk = t / (512 * NCT);
    int k = chunk * 32 + kq * 8 + jj;
    int j = ct * 16 + c;
    B[t] = (half_t)W[(size_t)j * C_IN + k];
}

// One 32-thread group per node; lane owns 4 halves of C=128.
__global__ __launch_bounds__(256) void gather_mean(
    const half_t* __restrict__ h, const int* __restrict__ row_ptr,
    const int* __restrict__ sorted_src, half_t* __restrict__ mean, int n) {
    int node = blockIdx.x * 8 + (threadIdx.x >> 5);
    if (node >= n) return;
    int lane = threadIdx.x & 31;
    int beg = row_ptr[node], end = row_ptr[node + 1];
    float ax = 0.f, ay = 0.f, az = 0.f, aw = 0.f;
    int j = beg;
    for (; j + 3 < end; j += 4) {
        int s0 = sorted_src[j], s1 = sorted_src[j + 1];
        int s2 = sorted_src[j + 2], s3 = sorted_src[j + 3];
        half4v v0 = *(const half4v*)(h + (size_t)s0 * 128 + lane * 4);
        half4v v1 = *(const half4v*)(h + (size_t)s1 * 128 + lane * 4);
        half4v v2 = *(const half4v*)(h + (size_t)s2 * 128 + lane * 4);
        half4v v3 = *(const half4v*)(h + (size_t)s3 * 128 + lane * 4);
        ax += ((float)v0.x + (float)v1.x) + ((float)v2.x + (float)v3.x);
        ay += ((float)v0.y + (float)v1.y) + ((float)v2.y + (float)v3.y);
        az += ((float)v0.z + (float)v1.z) + ((float)v2.z + (float)v3.z);
        aw += ((float)v0.w + (float)v1.w) + ((float)v2.w + (float)v3.w);
    }
    for (; j < end; j++) {
        int s0 = sorted_src[j];
        half4v v0 = *(const half4v*)(h + (size_t)s0 * 128 + lane * 4);
        ax += (float)v0.x; ay += (float)v0.y; az += (float)v0.z; aw += (float)v0.w;
    }
    float inv = (end > beg) ? 1.0f / (float)(end - beg) : 0.0f;
    half4v r = {(half_t)(ax * inv), (half_t)(ay * inv), (half_t)(az * inv), (half_t)(aw * inv)};
    *(half4v*)(mean + (size_t)node * 128 + lane * 4) = r;
}

// out[n][j] = relu?( mean[n]@Wl^T + bias + root[n]@Wr^T )
// Block: 256 thr = 4 waves; wave handles 16 rows x C_OUT. K = 128 per stage,
// chunks of 32 via mfma_f32_16x16x32_f16. A frags from global (lane's own row),
// B frags from prepped buffer (L1-hot).
template <int C_OUT, bool RELU, bool OUT32>
__global__ __launch_bounds__(256) void mfma_layer(
    const half_t* __restrict__ rootA, const half_t* __restrict__ meanA,
    const half_t* __restrict__ Bl, const half_t* __restrict__ Br,
    const float* __restrict__ bias, float* __restrict__ out32,
    half_t* __restrict__ out16, int n) {
    constexpr int NCT = C_OUT / 16;
    int tid = threadIdx.x;
    int w = tid >> 6;
    int l = tid & 63;
    int c = l & 15;   // A row-in-tile; D col-in-tile
    int q = l >> 4;   // quad
    int row = blockIdx.x * 64 + w * 16 + c;
    int rowc = min(row, n - 1);

    float4v acc[NCT];
#pragma unroll
    for (int i = 0; i < NCT; i++) acc[i] = (float4v){0.f, 0.f, 0.f, 0.f};

#pragma unroll
    for (int s = 0; s < 2; s++) {
        const half_t* A = (s == 0 ? meanA : rootA) + (size_t)rowc * 128 + q * 8;
        const half_t* B = (s == 0 ? Bl : Br) + (size_t)(c * 4 + q) * 8;
#pragma unroll
        for (int ch = 0; ch < 4; ch++) {
            half8v a = *(const half8v*)(A + ch * 32);
            half8v b[NCT];
#pragma unroll
            for (int t2 = 0; t2 < NCT; t2++)
                b[t2] = *(const half8v*)(B + (size_t)ch * (NCT * 512) + t2 * 512);
#pragma unroll
            for (int t2 = 0; t2 < NCT; t2++)
                acc[t2] = __builtin_amdgcn_mfma_f32_16x16x32_f16(a, b[t2], acc[t2], 0, 0, 0);
        }
    }

    // D: col = ct*16 + c, row = q*4 + r within the wave's 16-row tile
    int orow0 = blockIdx.x * 64 + w * 16 + q * 4;
#pragma unroll
    for (int t2 = 0; t2 < NCT; t2++) {
        int col = t2 * 16 + c;
        float bv = bias[col];
#pragma unroll
        for (int r = 0; r < 4; r++) {
            int nrow = orow0 + r;
            if (nrow < n) {
                float v = acc[t2][r] + bv;
                if (RELU) v = fmaxf(v, 0.f);
                if (OUT32) out32[(size_t)nrow * C_OUT + col] = v;
                else       out16[(size_t)nrow * C_OUT + col] = (half_t)v;
            }
        }
    }
}

extern "C" void kernel_launch(void* const* d_in, const int* in_sizes, int n_in,
                              void* d_out, int out_size, void* d_ws, size_t ws_size,
                              hipStream_t stream) {
    const float* x   = (const float*)d_in[0];
    const int*   ei  = (const int*)d_in[1];
    const float* Wl1 = (const float*)d_in[2];
    const float* bl1 = (const float*)d_in[3];
    const float* Wr1 = (const float*)d_in[4];
    const float* Wl2 = (const float*)d_in[5];
    const float* bl2 = (const float*)d_in[6];
    const float* Wr2 = (const float*)d_in[7];
    const float* Wl3 = (const float*)d_in[8];
    const float* bl3 = (const float*)d_in[9];
    const float* Wr3 = (const float*)d_in[10];

    const int N = NN;
    const int E = in_sizes[1] / 2;
    const int* src = ei;
    const int* dst = ei + E;

    char* ws = (char*)d_ws;
    half_t* xh   = (half_t*)ws;                       // N*128
    half_t* hh   = xh + (size_t)N * 128;              // N*128
    half_t* meanh = hh + (size_t)N * 128;             // N*128
    int* cnt     = (int*)(meanh + (size_t)N * 128);   // N
    int* row_ptr = cnt + N;                           // N+4 (padded for alignment)
    int* fill    = row_ptr + N + 4;                   // N
    int* sorted_src = fill + N;                       // E
    half_t* Bl1 = (half_t*)(sorted_src + E);          // 128*128 each
    half_t* Br1 = Bl1 + 128 * 128;
    half_t* Bl2 = Br1 + 128 * 128;
    half_t* Br2 = Bl2 + 128 * 128;
    half_t* Bl3 = Br2 + 128 * 128;                    // 64*128
    half_t* Br3 = Bl3 + 64 * 128;

    // Casts + weight prep (tiny)
    cast_f2h<<<(N * 128 / 4 + 255) / 256, 256, 0, stream>>>(x, xh, N * 128 / 4);
    prep_w<128, 128><<<64, 256, 0, stream>>>(Wl1, Bl1);
    prep_w<128, 128><<<64, 256, 0, stream>>>(Wr1, Br1);
    prep_w<128, 128><<<64, 256, 0, stream>>>(Wl2, Bl2);
    prep_w<128, 128><<<64, 256, 0, stream>>>(Wr2, Br2);
    prep_w<128, 64><<<32, 256, 0, stream>>>(Wl3, Bl3);
    prep_w<128, 64><<<32, 256, 0, stream>>>(Wr3, Br3);

    // CSR build
    hipMemsetAsync(cnt, 0, (size_t)N * 4, stream);
    count_kernel<<<(E + 255) / 256, 256, 0, stream>>>(dst, cnt, E);
    scan_kernel<<<1, 1024, 0, stream>>>(cnt, row_ptr, fill, N);
    bucket_kernel<<<(E + 255) / 256, 256, 0, stream>>>(src, dst, fill, sorted_src, E);

    const int agg_blocks = (N + 7) / 8;
    const int gemm_blocks = (N + 63) / 64;

    // Layer 1: xh -> hh (relu)
    gather_mean<<<agg_blocks, 256, 0, stream>>>(xh, row_ptr, sorted_src, meanh, N);
    mfma_layer<128, true, false><<<gemm_blocks, 256, 0, stream>>>(
        xh, meanh, Bl1, Br1, bl1, nullptr, hh, N);

    // Layer 2: hh -> hh (in place; each wave reads only its own 16 rows) (relu)
    gather_mean<<<agg_blocks, 256, 0, stream>>>(hh, row_ptr, sorted_src, meanh, N);
    mfma_layer<128, true, false><<<gemm_blocks, 256, 0, stream>>>(
        hh, meanh, Bl2, Br2, bl2, nullptr, hh, N);

    // Layer 3: hh -> d_out fp32 (no relu), C_OUT=64
    gather_mean<<<agg_blocks, 256, 0, stream>>>(hh, row_ptr, sorted_src, meanh, N);
    mfma_layer<64, false, true><<<gemm_blocks, 256, 0, stream>>>(
        hh, meanh, Bl3, Br3, bl3, (float*)d_out, nullptr, N);
}

// Round 4
// 685.603 us; speedup vs baseline: 24.2181x; 1.7456x over previous
//
#include <hip/hip_runtime.h>

// GraphSAGE 3-layer: N=100000, E=3.2M, 128 -> 128 -> 128 -> 64.
// Round 4: replace atomic CSR build (count+scan+bucket ~530us, random-atomic
// bound) with two-level LDS-privatized counting sort:
//   A: coarse hist (1024 bins = dst>>7), LDS-private, coalesced global merge
//   B: scan 1024 bins (single block) -> cptr/cfill; row_ptr[N]=E
//   C: partition chunks of 8192 edges locally by coarse bin (LDS sort),
//      packed u32 = (dst&127)<<17 | src, bulk space reservation, run writes
//   D: per-bucket fine sort (128 bins) -> row_ptr + sorted_src (coalesced-ish)
// gather_mean + mfma_layer unchanged from round 3.

#define NN 100000
#define CHUNK 8192

typedef _Float16 half_t;
typedef __attribute__((ext_vector_type(4))) _Float16 half4v;
typedef __attribute__((ext_vector_type(8))) _Float16 half8v;
typedef __attribute__((ext_vector_type(4))) float float4v;

// ---- Pass A: coarse histogram (LDS-privatized) ----
__global__ __launch_bounds__(256) void coarse_hist_kernel(const int* __restrict__ dst,
                                                          int* __restrict__ ghist, int E) {
    __shared__ int h[1024];
    int tid = threadIdx.x;
    for (int i = tid; i < 1024; i += 256) h[i] = 0;
    __syncthreads();
    int base = blockIdx.x * CHUNK;
    int nE = min(CHUNK, E - base);
    for (int i = tid; i < nE; i += 256) atomicAdd(&h[dst[base + i] >> 7], 1);
    __syncthreads();
    for (int i = tid; i < 1024; i += 256) {
        int v = h[i];
        if (v) atomicAdd(&ghist[i], v);
    }
}

// ---- Pass B: scan 1024 coarse bins ----
__global__ __launch_bounds__(1024) void coarse_scan_kernel(const int* __restrict__ ghist,
                                                           int* __restrict__ cptr,
                                                           int* __restrict__ cfill,
                                                           int* __restrict__ row_ptr,
                                                           int n, int E) {
    __shared__ int s[1024];
    int tid = threadIdx.x;
    s[tid] = ghist[tid];
    __syncthreads();
    for (int off = 1; off < 1024; off <<= 1) {
        int v = (tid >= off) ? s[tid - off] : 0;
        __syncthreads();
        s[tid] += v;
        __syncthreads();
    }
    int excl = (tid == 0) ? 0 : s[tid - 1];
    cptr[tid] = excl;
    cfill[tid] = excl;
    if (tid == 1023) {
        cptr[1024] = s[1023];
        row_ptr[n] = E;
    }
}

// ---- Pass C: partition edges into coarse buckets (packed u32) ----
__global__ __launch_bounds__(256) void partition_kernel(const int* __restrict__ src,
                                                        const int* __restrict__ dst,
                                                        int* __restrict__ cfill,
                                                        unsigned int* __restrict__ coarse,
                                                        int E) {
    __shared__ int h[1024];
    __shared__ int off[1024];
    __shared__ int gbase[1024];
    __shared__ int ssum[256];
    __shared__ unsigned int stage[CHUNK];
    int tid = threadIdx.x;
    for (int i = tid; i < 1024; i += 256) h[i] = 0;
    __syncthreads();
    int base = blockIdx.x * CHUNK;
    int nE = min(CHUNK, E - base);
    for (int i = tid; i < nE; i += 256) atomicAdd(&h[dst[base + i] >> 7], 1);
    __syncthreads();
    // exclusive scan of 1024 bins; thread owns bins 4t..4t+3
    int b0 = tid * 4;
    int sum = h[b0] + h[b0 + 1] + h[b0 + 2] + h[b0 + 3];
    ssum[tid] = sum;
    __syncthreads();
    for (int o = 1; o < 256; o <<= 1) {
        int v = (tid >= o) ? ssum[tid - o] : 0;
        __syncthreads();
        ssum[tid] += v;
        __syncthreads();
    }
    int run = (tid == 0) ? 0 : ssum[tid - 1];
#pragma unroll
    for (int j = 0; j < 4; j++) { off[b0 + j] = run; run += h[b0 + j]; }
    __syncthreads();
    // local scatter into stage (sorted by coarse bin)
    for (int i = tid; i < nE; i += 256) {
        int d = dst[base + i];
        int s_ = src[base + i];
        int bin = d >> 7;
        int pos = atomicAdd(&off[bin], 1);
        stage[pos] = ((unsigned)(d & 127) << 17) | (unsigned)s_;
    }
    __syncthreads();
    // reserve global space per bin (off[b] is now local end)
#pragma unroll
    for (int j = 0; j < 4; j++) {
        int b = b0 + j;
        if (h[b]) gbase[b] = atomicAdd(&cfill[b], h[b]);
    }
    // write out this block's run for each owned bin
#pragma unroll
    for (int j = 0; j < 4; j++) {
        int b = b0 + j;
        int c = h[b];
        int lstart = off[b] - c;
        int gs = gbase[b];
        for (int k = 0; k < c; k++) coarse[gs + k] = stage[lstart + k];
    }
}

// ---- Pass D: fine sort within each coarse bucket; emits row_ptr + sorted_src ----
__global__ __launch_bounds__(256) void fine_sort_kernel(const unsigned int* __restrict__ coarse,
                                                        const int* __restrict__ cptr,
                                                        int* __restrict__ row_ptr,
                                                        int* __restrict__ sorted_src, int n) {
    __shared__ int fh[128];
    __shared__ int foff[128];
    int b = blockIdx.x;
    int beg = cptr[b], end = cptr[b + 1];
    int nb = end - beg;
    int tid = threadIdx.x;
    if (tid < 128) fh[tid] = 0;
    __syncthreads();
    for (int i = tid; i < nb; i += 256) atomicAdd(&fh[coarse[beg + i] >> 17], 1);
    __syncthreads();
    if (tid < 128) foff[tid] = fh[tid];
    __syncthreads();
    for (int o = 1; o < 128; o <<= 1) {
        int v = 0;
        if (tid < 128 && tid >= o) v = foff[tid - o];
        __syncthreads();
        if (tid < 128) foff[tid] += v;
        __syncthreads();
    }
    if (tid < 128) {
        int node = b * 128 + tid;
        if (node < n) row_ptr[node] = beg + foff[tid] - fh[tid];
        foff[tid] -= fh[tid];  // exclusive -> fill counter
    }
    __syncthreads();
    for (int i = tid; i < nb; i += 256) {
        unsigned int p = coarse[beg + i];
        int f = p >> 17;
        int pos = atomicAdd(&foff[f], 1);
        sorted_src[beg + pos] = (int)(p & 0x1FFFF);
    }
}

// ---- fp32 -> fp16 cast ----
__global__ void cast_f2h(const float* __restrict__ in, half_t* __restrict__ out, int n4) {
    int t = blockIdx.x * blockDim.x + threadIdx.x;
    if (t < n4) {
        float4 v = *(const float4*)(in + (size_t)t * 4);
        half4v r = {(half_t)v.x, (half_t)v.y, (half_t)v.z, (half_t)v.w};
        *(half4v*)(out + (size_t)t * 4) = r;
    }
}

// ---- weight prep: fragment-contiguous fp16 ----
template <int C_IN, int C_OUT>
__global__ void prep_w(const float* __restrict__ W, half_t* __restrict__ B) {
    constexpr int NCT = C_OUT / 16;
    int t = blockIdx.x * blockDim.x + threadIdx.x;
    if (t >= C_IN * C_OUT) return;
    int jj = t & 7;
    int kq = (t >> 3) & 3;
    int c = (t >> 5) & 15;
    int ct = (t >> 9) % NCT;
    int chunk = t / (512 * NCT);
    int k = chunk * 32 + kq * 8 + jj;
    int j = ct * 16 + c;
    B[t] = (half_t)W[(size_t)j * C_IN + k];
}

// ---- gather mean (fp16, fp32 acc) ----
__global__ __launch_bounds__(256) void gather_mean(
    const half_t* __restrict__ h, const int* __restrict__ row_ptr,
    const int* __restrict__ sorted_src, half_t* __restrict__ mean, int n) {
    int node = blockIdx.x * 8 + (threadIdx.x >> 5);
    if (node >= n) return;
    int lane = threadIdx.x & 31;
    int beg = row_ptr[node], end = row_ptr[node + 1];
    float ax = 0.f, ay = 0.f, az = 0.f, aw = 0.f;
    int j = beg;
    for (; j + 3 < end; j += 4) {
        int s0 = sorted_src[j], s1 = sorted_src[j + 1];
        int s2 = sorted_src[j + 2], s3 = sorted_src[j + 3];
        half4v v0 = *(const half4v*)(h + (size_t)s0 * 128 + lane * 4);
        half4v v1 = *(const half4v*)(h + (size_t)s1 * 128 + lane * 4);
        half4v v2 = *(const half4v*)(h + (size_t)s2 * 128 + lane * 4);
        half4v v3 = *(const half4v*)(h + (size_t)s3 * 128 + lane * 4);
        ax += ((float)v0.x + (float)v1.x) + ((float)v2.x + (float)v3.x);
        ay += ((float)v0.y + (float)v1.y) + ((float)v2.y + (float)v3.y);
        az += ((float)v0.z + (float)v1.z) + ((float)v2.z + (float)v3.z);
        aw += ((float)v0.w + (float)v1.w) + ((float)v2.w + (float)v3.w);
    }
    for (; j < end; j++) {
        int s0 = sorted_src[j];
        half4v v0 = *(const half4v*)(h + (size_t)s0 * 128 + lane * 4);
        ax += (float)v0.x; ay += (float)v0.y; az += (float)v0.z; aw += (float)v0.w;
    }
    float inv = (end > beg) ? 1.0f / (float)(end - beg) : 0.0f;
    half4v r = {(half_t)(ax * inv), (half_t)(ay * inv), (half_t)(az * inv), (half_t)(aw * inv)};
    *(half4v*)(mean + (size_t)node * 128 + lane * 4) = r;
}

// ---- MFMA layer: out = relu?( mean@Wl^T + bias + root@Wr^T ) ----
template <int C_OUT, bool RELU, bool OUT32>
__global__ __launch_bounds__(256) void mfma_layer(
    const half_t* __restrict__ rootA, const half_t* __restrict__ meanA,
    const half_t* __restrict__ Bl, const half_t* __restrict__ Br,
    const float* __restrict__ bias, float* __restrict__ out32,
    half_t* __restrict__ out16, int n) {
    constexpr int NCT = C_OUT / 16;
    int tid = threadIdx.x;
    int w = tid >> 6;
    int l = tid & 63;
    int c = l & 15;
    int q = l >> 4;
    int row = blockIdx.x * 64 + w * 16 + c;
    int rowc = min(row, n - 1);

    float4v acc[NCT];
#pragma unroll
    for (int i = 0; i < NCT; i++) acc[i] = (float4v){0.f, 0.f, 0.f, 0.f};

#pragma unroll
    for (int s = 0; s < 2; s++) {
        const half_t* A = (s == 0 ? meanA : rootA) + (size_t)rowc * 128 + q * 8;
        const half_t* B = (s == 0 ? Bl : Br) + (size_t)(c * 4 + q) * 8;
#pragma unroll
        for (int ch = 0; ch < 4; ch++) {
            half8v a = *(const half8v*)(A + ch * 32);
            half8v b[NCT];
#pragma unroll
            for (int t2 = 0; t2 < NCT; t2++)
                b[t2] = *(const half8v*)(B + (size_t)ch * (NCT * 512) + t2 * 512);
#pragma unroll
            for (int t2 = 0; t2 < NCT; t2++)
                acc[t2] = __builtin_amdgcn_mfma_f32_16x16x32_f16(a, b[t2], acc[t2], 0, 0, 0);
        }
    }

    int orow0 = blockIdx.x * 64 + w * 16 + q * 4;
#pragma unroll
    for (int t2 = 0; t2 < NCT; t2++) {
        int col = t2 * 16 + c;
        float bv = bias[col];
#pragma unroll
        for (int r = 0; r < 4; r++) {
            int nrow = orow0 + r;
            if (nrow < n) {
                float v = acc[t2][r] + bv;
                if (RELU) v = fmaxf(v, 0.f);
                if (OUT32) out32[(size_t)nrow * C_OUT + col] = v;
                else       out16[(size_t)nrow * C_OUT + col] = (half_t)v;
            }
        }
    }
}

extern "C" void kernel_launch(void* const* d_in, const int* in_sizes, int n_in,
                              void* d_out, int out_size, void* d_ws, size_t ws_size,
                              hipStream_t stream) {
    const float* x   = (const float*)d_in[0];
    const int*   ei  = (const int*)d_in[1];
    const float* Wl1 = (const float*)d_in[2];
    const float* bl1 = (const float*)d_in[3];
    const float* Wr1 = (const float*)d_in[4];
    const float* Wl2 = (const float*)d_in[5];
    const float* bl2 = (const float*)d_in[6];
    const float* Wr2 = (const float*)d_in[7];
    const float* Wl3 = (const float*)d_in[8];
    const float* bl3 = (const float*)d_in[9];
    const float* Wr3 = (const float*)d_in[10];

    const int N = NN;
    const int E = in_sizes[1] / 2;
    const int* src = ei;
    const int* dst = ei + E;

    char* ws = (char*)d_ws;
    half_t* xh    = (half_t*)ws;                      // N*128
    half_t* hh    = xh + (size_t)N * 128;             // N*128
    half_t* meanh = hh + (size_t)N * 128;             // N*128
    int* ghist    = (int*)(meanh + (size_t)N * 128);  // 1024
    int* cptr     = ghist + 1024;                     // 1025 (pad 1028)
    int* cfill    = cptr + 1028;                      // 1024
    int* row_ptr  = cfill + 1024;                     // N+1 (pad N+4)
    unsigned int* coarse = (unsigned int*)(row_ptr + N + 4);  // E
    int* sorted_src = (int*)(coarse + E);             // E
    half_t* Bl1 = (half_t*)(sorted_src + E);
    half_t* Br1 = Bl1 + 128 * 128;
    half_t* Bl2 = Br1 + 128 * 128;
    half_t* Br2 = Bl2 + 128 * 128;
    half_t* Bl3 = Br2 + 128 * 128;                    // 64*128
    half_t* Br3 = Bl3 + 64 * 128;

    // casts + weight prep (tiny)
    cast_f2h<<<(N * 128 / 4 + 255) / 256, 256, 0, stream>>>(x, xh, N * 128 / 4);
    prep_w<128, 128><<<64, 256, 0, stream>>>(Wl1, Bl1);
    prep_w<128, 128><<<64, 256, 0, stream>>>(Wr1, Br1);
    prep_w<128, 128><<<64, 256, 0, stream>>>(Wl2, Bl2);
    prep_w<128, 128><<<64, 256, 0, stream>>>(Wr2, Br2);
    prep_w<128, 64><<<32, 256, 0, stream>>>(Wl3, Bl3);
    prep_w<128, 64><<<32, 256, 0, stream>>>(Wr3, Br3);

    // CSR build: two-level counting sort
    const int sort_blocks = (E + CHUNK - 1) / CHUNK;
    hipMemsetAsync(ghist, 0, 1024 * 4, stream);
    coarse_hist_kernel<<<sort_blocks, 256, 0, stream>>>(dst, ghist, E);
    coarse_scan_kernel<<<1, 1024, 0, stream>>>(ghist, cptr, cfill, row_ptr, N, E);
    partition_kernel<<<sort_blocks, 256, 0, stream>>>(src, dst, cfill, coarse, E);
    fine_sort_kernel<<<(N + 127) / 128, 256, 0, stream>>>(coarse, cptr, row_ptr, sorted_src, N);

    const int agg_blocks = (N + 7) / 8;
    const int gemm_blocks = (N + 63) / 64;

    // Layer 1: xh -> hh (relu)
    gather_mean<<<agg_blocks, 256, 0, stream>>>(xh, row_ptr, sorted_src, meanh, N);
    mfma_layer<128, true, false><<<gemm_blocks, 256, 0, stream>>>(
        xh, meanh, Bl1, Br1, bl1, nullptr, hh, N);

    // Layer 2: hh -> hh (relu)
    gather_mean<<<agg_blocks, 256, 0, stream>>>(hh, row_ptr, sorted_src, meanh, N);
    mfma_layer<128, true, false><<<gemm_blocks, 256, 0, stream>>>(
        hh, meanh, Bl2, Br2, bl2, nullptr, hh, N);

    // Layer 3: hh -> d_out fp32 (no relu)
    gather_mean<<<agg_blocks, 256, 0, stream>>>(hh, row_ptr, sorted_src, meanh, N);
    mfma_layer<64, false, true><<<gemm_blocks, 256, 0, stream>>>(
        hh, meanh, Bl3, Br3, bl3, (float*)d_out, nullptr, N);
}